// Round 11
// baseline (215.583 us; speedup 1.0000x reference)
//
#include <hip/hip_runtime.h>
#include <stdint.h>

#define DM   1024
#define NH   16
#define DKH  64
#define SEQ  2048
#define NB   2

typedef __attribute__((ext_vector_type(8))) short  frag8;
typedef __attribute__((ext_vector_type(4))) short  frag4;
typedef __attribute__((ext_vector_type(4))) short  short4v;
typedef __attribute__((ext_vector_type(8))) short  short8v;
typedef __attribute__((ext_vector_type(4))) float  f32x4;

__device__ __forceinline__ unsigned short f2bf(float x){
  unsigned u = __float_as_uint(x);
  u += 0x7fffu + ((u >> 16) & 1u);
  return (unsigned short)(u >> 16);
}

// exp2 via the raw intrinsic (v_exp_f32) — avoids glibc __exp2f macro collision
__device__ __forceinline__ float dev_exp2(float x){
  return __builtin_amdgcn_exp2f(x);
}

#define GLOAD16(GP, LP) __builtin_amdgcn_global_load_lds( \
    (__attribute__((address_space(1))) void*)(GP), \
    (__attribute__((address_space(3))) void*)(LP), 16, 0, 0)

// Compiler memory fence (zero instructions): raw s_barrier is NOT an LLVM memory
// fence, so dependent LDS reads can be hoisted above it. Pin them below.
#define LDSFENCE() do{ asm volatile("" ::: "memory"); \
                       __builtin_amdgcn_sched_barrier(0); }while(0)

// NOTE (bisect r0-r5): v_cvt_pk_bf16_f32 inline-asm pack FAILED 3/3; manual
// element-wise pack passed every time. r10: the or/shift u32 pack rewrite
// REGRESSED flash 5% (serialized deps, no v_perm fold) -> reverted here.
// NOTE (r7): occupancy must come from waves/block, not more blocks per head.
// NOTE (r8/r9/r10): 8-wave same-grid transform won on flash, gemm_bt, gemm64_bt.
// NOTE (r10 model): flash LDS traffic = waves/CU x 32 x 16KB (each wave reads
// the full K+V tile); 16 waves -> ~62% LDS-busy. Both fewer-waves (latency) and
// more-waves (LDS) regimes floor at ~47-50us for this decomposition.

// 16B XOR swizzle: LDS granule g of row r holds global granule g^(r&7);
// staging loads global granule (lane&7)^row. (R4: conflicts -> 0 on b128 reads.)

// ---------------- fused: cast fp32->bf16 (z=0..2) + weight transpose (z=3..6) ----
__global__ __launch_bounds__(256) void castw(const float* __restrict__ Q,
                                             const float* __restrict__ K,
                                             const float* __restrict__ V,
                                             const float* __restrict__ Wq,
                                             const float* __restrict__ Wk,
                                             const float* __restrict__ Wv,
                                             const float* __restrict__ Wo,
                                             short* __restrict__ xc,
                                             short* __restrict__ wt){
  const int z = blockIdx.z;
  __shared__ float t[32][33];
  if (z < 3){
    const float* src = (z == 0) ? Q : (z == 1 ? K : V);
    const int i = (blockIdx.x * 256 + threadIdx.x) * 4;
    float4 f = *(const float4*)(src + i);
    short4v s;
    s.x = (short)f2bf(f.x); s.y = (short)f2bf(f.y);
    s.z = (short)f2bf(f.z); s.w = (short)f2bf(f.w);
    *(short4v*)(xc + (long)z * (SEQ*NB*DM) + i) = s;
  } else {
    const int bx = blockIdx.x;
    if (bx >= 1024) return;
    const int wz = z - 3;
    const float* W = (wz == 0) ? Wq : (wz == 1 ? Wk : (wz == 2 ? Wv : Wo));
    short* out = wt + (long)wz * (DM*DM);
    const int n0 = (bx & 31) * 32, k0 = (bx >> 5) * 32;
    const int c = threadIdx.x & 31, r0 = threadIdx.x >> 5;
#pragma unroll
    for (int i = 0; i < 4; ++i){
      int r = r0 + i * 8;
      t[r][c] = W[(k0 + r) * DM + n0 + c];
    }
    __syncthreads();
#pragma unroll
    for (int i = 0; i < 4; ++i){
      int r = r0 + i * 8;
      out[(n0 + r) * DM + k0 + c] = (short)f2bf(t[c][r]);
    }
  }
}

// ---------------- 128x128 bf16 MFMA GEMM: C = A(M,K) * Bt(N,K)^T, +bias, *scale ----
// 8 waves/block (512 thr), 128x128 tile, wave = 32x64 sub-tile (proven r9).
// 2-buffer LDS + counted vmcnt: STAGE(t+1) -> vmcnt(4) -> barrier -> fence ->
// COMPUTE(t) -> lgkmcnt(0) -> barrier.
__device__ __forceinline__ void store_out(short* p, float v){ *p = (short)f2bf(v); }
__device__ __forceinline__ void store_out(float* p, float v){ *p = v; }

template<typename OT>
__global__ __launch_bounds__(512) void gemm_bt(const short* __restrict__ Abase, long Astride,
                                               const short* __restrict__ Btbase, long Btstride,
                                               const float* __restrict__ bias0,
                                               const float* __restrict__ bias1,
                                               const float* __restrict__ bias2,
                                               OT* __restrict__ Cbase, long Cstride,
                                               float qscale){
  const int z = blockIdx.z;
  const short* A  = Abase + (long)z * Astride;
  const short* Bt = Btbase + (long)z * Btstride;
  OT* C = Cbase + (long)z * Cstride;
  const float* bias = (z == 0) ? bias0 : (z == 1 ? bias1 : bias2);
  const float scale = (z == 0) ? qscale : 1.0f;
  const int KD = DM, ND = DM;

  __shared__ __align__(16) short As[2][128 * 64];
  __shared__ __align__(16) short Bs[2][128 * 64];

  const int tid = threadIdx.x;
  const int w = tid >> 6, lane = tid & 63, l15 = lane & 15, quad = lane >> 4;
  const int wy = w >> 1, wx = w & 1;            // 4 x 2 wave grid, 32x64 each
  const int bm = blockIdx.x * 128, bn = blockIdx.y * 128;
  const int lrow = lane >> 3;
  const int lcolsw = (((lane & 7) ^ lrow) & 7) * 8;   // swizzled source granule

  f32x4 acc[2][4] = {};

#define GSTAGE(KT, BSEL) do{                                                    \
  _Pragma("unroll")                                                             \
  for (int i_ = 0; i_ < 2; ++i_){                                               \
    int j_ = w * 2 + i_;                                                        \
    GLOAD16(A  + (bm + j_ * 8 + lrow) * KD + (KT) * 64 + lcolsw,                \
            &As[BSEL][j_ * 512]);                                               \
    GLOAD16(Bt + (bn + j_ * 8 + lrow) * KD + (KT) * 64 + lcolsw,                \
            &Bs[BSEL][j_ * 512]);                                               \
  } }while(0)

#define GCOMPUTE(BS) do{                                                        \
  _Pragma("unroll") for (int ks = 0; ks < 2; ++ks){                             \
    frag8 af[2], bf_[4];                                                        \
    _Pragma("unroll") for (int mt = 0; mt < 2; ++mt)                            \
      af[mt] = *(const frag8*)&As[BS][(wy * 32 + mt * 16 + l15) * 64 +          \
                                      (((ks * 4 + quad) ^ (l15 & 7)) * 8)];     \
    _Pragma("unroll") for (int nt = 0; nt < 4; ++nt)                            \
      bf_[nt] = *(const frag8*)&Bs[BS][(wx * 64 + nt * 16 + l15) * 64 +         \
                                       (((ks * 4 + quad) ^ (l15 & 7)) * 8)];    \
    _Pragma("unroll") for (int mt = 0; mt < 2; ++mt)                            \
      _Pragma("unroll") for (int nt = 0; nt < 4; ++nt)                          \
        acc[mt][nt] = __builtin_amdgcn_mfma_f32_16x16x32_bf16(                  \
            af[mt], bf_[nt], acc[mt][nt], 0, 0, 0);                             \
  } }while(0)

  GSTAGE(0, 0);
  for (int t = 0; t < KD / 64 - 1; ++t){       // 15 pipelined iterations
    GSTAGE(t + 1, (t + 1) & 1);
    asm volatile("s_waitcnt vmcnt(4)" ::: "memory");
    __builtin_amdgcn_s_barrier();
    LDSFENCE();
    GCOMPUTE(t & 1);
    asm volatile("s_waitcnt lgkmcnt(0)" ::: "memory");
    __builtin_amdgcn_sched_barrier(0);
    __builtin_amdgcn_s_barrier();
  }
  asm volatile("s_waitcnt vmcnt(0)" ::: "memory");
  __builtin_amdgcn_s_barrier();
  LDSFENCE();
  GCOMPUTE(1);                                  // tile 15 (odd)

#undef GSTAGE
#undef GCOMPUTE

#pragma unroll
  for (int mt = 0; mt < 2; ++mt){
#pragma unroll
    for (int r = 0; r < 4; ++r){
      int m = bm + wy * 32 + mt * 16 + quad * 4 + r;
#pragma unroll
      for (int nt = 0; nt < 4; ++nt){
        int n = bn + wx * 64 + nt * 16 + l15;
        float v = (acc[mt][nt][r] + bias[n]) * scale;
        store_out(&C[(long)m * ND + n], v);
      }
    }
  }
}

// ---------------- 64x128-tile GEMM (for low-block-count output projection) -------
// 8 waves/block (512 thr), wave = 16x64 (acc[1][4]); counted vmcnt(3). (r10)
template<typename OT>
__global__ __launch_bounds__(512) void gemm64_bt(const short* __restrict__ A,
                                                 const short* __restrict__ Bt,
                                                 const float* __restrict__ bias,
                                                 OT* __restrict__ C,
                                                 float scale){
  const int KD = DM, ND = DM;
  __shared__ __align__(16) short As[2][64 * 64];
  __shared__ __align__(16) short Bs[2][128 * 64];
  const int tid = threadIdx.x;
  const int w = tid >> 6, lane = tid & 63, l15 = lane & 15, quad = lane >> 4;
  const int wy = w >> 1, wx = w & 1;            // 4 x 2 wave grid, 16x64 each
  const int bm = blockIdx.x * 64, bn = blockIdx.y * 128;
  const int lrow = lane >> 3;
  const int lcolsw = (((lane & 7) ^ lrow) & 7) * 8;
  f32x4 acc[4] = {};

#define GSTAGE64(KT, BSEL) do{                                                  \
  {                                                                             \
    int j_ = w;                                                                 \
    GLOAD16(A + (bm + j_ * 8 + lrow) * KD + (KT) * 64 + lcolsw,                 \
            &As[BSEL][j_ * 512]);                                               \
  }                                                                             \
  _Pragma("unroll")                                                             \
  for (int i_ = 0; i_ < 2; ++i_){                                               \
    int j_ = w * 2 + i_;                                                        \
    GLOAD16(Bt + (bn + j_ * 8 + lrow) * KD + (KT) * 64 + lcolsw,                \
            &Bs[BSEL][j_ * 512]);                                               \
  } }while(0)

#define GCOMPUTE64(BS) do{                                                      \
  _Pragma("unroll") for (int ks = 0; ks < 2; ++ks){                             \
    frag8 af, bf_[4];                                                           \
    af = *(const frag8*)&As[BS][(wy * 16 + l15) * 64 +                          \
                                (((ks * 4 + quad) ^ (l15 & 7)) * 8)];           \
    _Pragma("unroll") for (int nt = 0; nt < 4; ++nt)                            \
      bf_[nt] = *(const frag8*)&Bs[BS][(wx * 64 + nt * 16 + l15) * 64 +         \
                                       (((ks * 4 + quad) ^ (l15 & 7)) * 8)];    \
    _Pragma("unroll") for (int nt = 0; nt < 4; ++nt)                            \
      acc[nt] = __builtin_amdgcn_mfma_f32_16x16x32_bf16(                        \
          af, bf_[nt], acc[nt], 0, 0, 0);                                       \
  } }while(0)

  GSTAGE64(0, 0);
  for (int t = 0; t < KD / 64 - 1; ++t){
    GSTAGE64(t + 1, (t + 1) & 1);
    asm volatile("s_waitcnt vmcnt(3)" ::: "memory");
    __builtin_amdgcn_s_barrier();
    LDSFENCE();
    GCOMPUTE64(t & 1);
    asm volatile("s_waitcnt lgkmcnt(0)" ::: "memory");
    __builtin_amdgcn_sched_barrier(0);
    __builtin_amdgcn_s_barrier();
  }
  asm volatile("s_waitcnt vmcnt(0)" ::: "memory");
  __builtin_amdgcn_s_barrier();
  LDSFENCE();
  GCOMPUTE64(1);

#undef GSTAGE64
#undef GCOMPUTE64

#pragma unroll
  for (int r = 0; r < 4; ++r){
    int m = bm + wy * 16 + quad * 4 + r;
#pragma unroll
    for (int nt = 0; nt < 4; ++nt){
      int n = bn + wx * 64 + nt * 16 + l15;
      store_out(&C[(long)m * ND + n], (acc[nt][r] + bias[n]) * scale);
    }
  }
}

// ---------------- v (B*S, DM) -> vt (B,H,Dk,S) bf16 transpose ----------------
__global__ __launch_bounds__(256) void vtrans(const short* __restrict__ v,
                                              short* __restrict__ vt){
  const int bh = blockIdx.y;       // b*16+h
  const int b = bh >> 4, h = bh & 15;
  const int s0 = blockIdx.x * 64;
  __shared__ short tT[64][66];
  const short* vb = v + ((long)(b * SEQ + s0)) * DM + h * DKH;
  for (int j = threadIdx.x; j < 512; j += 256){
    int row = j >> 3, off = (j & 7) * 8;
    short8v d = *(const short8v*)(vb + row * DM + off);
#pragma unroll
    for (int e = 0; e < 8; ++e) tT[off + e][row] = d[e];
  }
  __syncthreads();
  short* out = vt + (long)bh * (DKH * SEQ) + s0;
  for (int j = threadIdx.x; j < 512; j += 256){
    int dr = j >> 3, soff = (j & 7) * 8;
    short8v o;
#pragma unroll
    for (int e = 0; e < 8; ++e) o[e] = tT[dr][soff + e];
    *(short8v*)(out + dr * SEQ + soff) = o;
  }
}

// ---------------- flash attention v16 (r9, proven 47.5us) -------------------------
// 8 waves/block (512 thr), QBLK=128, 16 Q-rows/wave; grid 512 blocks; LDS 48KB
// 3-buffer depth-2 counted vmcnt(4); K-permutation + XOR swizzle + ELEMENT-WISE
// manual pack (r10's u32 pack rewrite regressed 5% -> reverted).
__global__ __launch_bounds__(512) void flash(const short* __restrict__ q,
                                             const short* __restrict__ k,
                                             const short* __restrict__ vt,
                                             short* __restrict__ comb){
  const int bh = blockIdx.y;
  const int b = bh >> 4, h = bh & 15;
  const int q0 = blockIdx.x * 128;         // 128 Q-rows per block, 16 per wave
  const int tid = threadIdx.x;
  const int w = tid >> 6, lane = tid & 63, l15 = lane & 15, quad = lane >> 4;

  __shared__ __align__(16) short Ks[3][64 * 64];
  __shared__ __align__(16) short Vs[3][64 * 64];

  // preload Q fragments straight from global (used as MFMA B operand)
  frag8 aq[2];
  const short* qb = q + ((long)(b * SEQ + q0 + w * 16)) * DM + h * DKH;
#pragma unroll
  for (int ks = 0; ks < 2; ++ks)
    aq[ks] = *(const frag8*)(qb + l15 * DM + ks * 32 + quad * 8);

  frag8 ones8;
#pragma unroll
  for (int e = 0; e < 8; ++e) ones8[e] = (short)0x3F80;  // bf16 1.0

  f32x4 O[4] = {};
  f32x4 Lacc = {0.f, 0.f, 0.f, 0.f};

  const short* kb  = k + ((long)b * SEQ) * DM + h * DKH;
  const short* vtb = vt + (long)bh * (DKH * SEQ);
  const int lrow8 = lane >> 3;
  const int lcolsw = (((lane & 7) ^ lrow8) & 7) * 8;   // 16B XOR swizzle

// stage tile KT into buffer BSEL; each of the 8 waves stages 8 K-rows + 8 V-rows.
// K rows permuted per the frag8-PV layout: LDS row p holds key
// a(p) = 32*(p>>5) + 8*((p>>2)&3) + 4*((p>>4)&1) + (p&3), p = jj*8+lrow8, jj=w.
#define STAGE(KT, BSEL) do{                                                     \
  int jj_ = w;                                                                  \
  int kr_ = 32 * (jj_ >> 2) + 8 * ((jj_ * 2 + (lrow8 >> 2)) & 3)                \
          + 4 * ((jj_ >> 1) & 1) + (lrow8 & 3);                                 \
  GLOAD16(kb  + ((KT) * 64 + kr_) * DM + lcolsw,        &Ks[BSEL][jj_ * 512]);  \
  GLOAD16(vtb + (jj_ * 8 + lrow8) * SEQ + (KT) * 64 + lcolsw,                   \
          &Vs[BSEL][jj_ * 512]);                                                \
}while(0)

#define COMPUTE(BS) do{                                                         \
  __builtin_amdgcn_s_setprio(1);                                                \
  f32x4 scT[4];                                                                 \
  _Pragma("unroll") for (int nt = 0; nt < 4; ++nt)                              \
    scT[nt] = (f32x4){0.f, 0.f, 0.f, 0.f};                                      \
  _Pragma("unroll") for (int ks = 0; ks < 2; ++ks){                             \
    _Pragma("unroll") for (int nt = 0; nt < 4; ++nt){                           \
      frag8 ak = *(const frag8*)&Ks[BS][(nt * 16 + l15) * 64 +                  \
                                        (((ks * 4 + quad) ^ (l15 & 7)) * 8)];   \
      scT[nt] = __builtin_amdgcn_mfma_f32_16x16x32_bf16(                        \
          ak, aq[ks], scT[nt], 0, 0, 0);                                        \
    }                                                                           \
  }                                                                             \
  frag8 ap8[2];                                                                 \
  _Pragma("unroll") for (int c2 = 0; c2 < 2; ++c2){                             \
    frag8 p8;                                                                   \
    _Pragma("unroll") for (int hf = 0; hf < 2; ++hf)                            \
      _Pragma("unroll") for (int r = 0; r < 4; ++r){                            \
        float e = dev_exp2(scT[2 * c2 + hf][r]);                                \
        p8[hf * 4 + r] = (short)((__float_as_uint(e) + 0x8000u) >> 16);         \
      }                                                                         \
    ap8[c2] = p8;                                                               \
  }                                                                             \
  _Pragma("unroll") for (int c2 = 0; c2 < 2; ++c2){                             \
    _Pragma("unroll") for (int dt = 0; dt < 4; ++dt){                           \
      frag8 bv8 = *(const frag8*)&Vs[BS][(dt * 16 + l15) * 64 +                 \
                                         (((c2 * 4 + quad) ^ (l15 & 7)) * 8)];  \
      O[dt] = __builtin_amdgcn_mfma_f32_16x16x32_bf16(                          \
          ap8[c2], bv8, O[dt], 0, 0, 0);                                        \
    }                                                                           \
    Lacc = __builtin_amdgcn_mfma_f32_16x16x32_bf16(                             \
        ap8[c2], ones8, Lacc, 0, 0, 0);                                         \
  }                                                                             \
  __builtin_amdgcn_s_setprio(0);                                                \
}while(0)

// stage KT+2, wait tile KT (vmcnt(4): leaves the 4 loads of KT+1/KT+2 in
// flight), barrier, fence, compute KT, lgkm-drain + barrier (WAR publish)
#define ITER(KT, BC, BSNEXT) do{                                                \
  STAGE((KT) + 2, BSNEXT);                                                      \
  asm volatile("s_waitcnt vmcnt(4)" ::: "memory");                              \
  __builtin_amdgcn_s_barrier();                                                 \
  LDSFENCE();                                                                   \
  COMPUTE(BC);                                                                  \
  asm volatile("s_waitcnt lgkmcnt(0)" ::: "memory");                            \
  __builtin_amdgcn_sched_barrier(0);                                            \
  __builtin_amdgcn_s_barrier();                                                 \
}while(0)

  STAGE(0, 0);
  STAGE(1, 1);
  for (int kt = 0; kt < SEQ / 64 - 2; kt += 3){   // 30 iterations, tiles 0..29
    ITER(kt,     0, 2);
    ITER(kt + 1, 1, 0);
    ITER(kt + 2, 2, 1);
  }
  // epilogue: tiles 30 (buf 0) and 31 (buf 1), no further staging
  asm volatile("s_waitcnt vmcnt(2)" ::: "memory");
  __builtin_amdgcn_s_barrier();
  LDSFENCE();
  COMPUTE(0);
  asm volatile("s_waitcnt vmcnt(0)" ::: "memory");
  __builtin_amdgcn_s_barrier();
  LDSFENCE();
  COMPUTE(1);

#undef ITER
#undef COMPUTE
#undef STAGE

  // epilogue: O/l -> comb bf16  (C-layout: row = quad*4+r = qrow, col = l15 = d)
  short* ob = comb + ((long)(b * SEQ + q0 + w * 16)) * DM + h * DKH;
#pragma unroll
  for (int r = 0; r < 4; ++r){
    float inv = 1.f / Lacc[r];
#pragma unroll
    for (int dt = 0; dt < 4; ++dt)
      ob[(quad * 4 + r) * DM + dt * 16 + l15] = (short)f2bf(O[dt][r] * inv);
  }
}

// ---------------- launch ----------------
extern "C" void kernel_launch(void* const* d_in, const int* in_sizes, int n_in,
                              void* d_out, int out_size, void* d_ws, size_t ws_size,
                              hipStream_t stream){
  const float* Q  = (const float*)d_in[0];
  const float* K  = (const float*)d_in[1];
  const float* V  = (const float*)d_in[2];
  const float* Wq = (const float*)d_in[3];
  const float* bq = (const float*)d_in[4];
  const float* Wk = (const float*)d_in[5];
  const float* bk = (const float*)d_in[6];
  const float* Wv = (const float*)d_in[7];
  const float* bv = (const float*)d_in[8];
  const float* Wo = (const float*)d_in[9];
  const float* bo = (const float*)d_in[10];
  float* out = (float*)d_out;

  const long TEN = (long)NB * SEQ * DM;   // 4194304 elements per activation tensor
  const long WEL = (long)DM * DM;         // 1048576 per weight
  short* ws   = (short*)d_ws;
  short* xc   = ws;                 // 3 * TEN
  short* wt   = xc + 3 * TEN;       // 4 * WEL
  short* qkv  = wt + 4 * WEL;       // 3 * TEN   (q, k, v projections, bf16)
  short* vtr  = qkv + 3 * TEN;      // TEN       (B,H,Dk,S)
  short* comb = vtr + TEN;          // TEN

  // fused cast (z 0..2) + weight transpose (z 3..6): one launch, independent work
  castw<<<dim3(4096, 1, 7), 256, 0, stream>>>(Q, K, V, Wq, Wk, Wv, Wo, xc, wt);
  // projections: z=0 -> q (scaled by log2e/sqrt(Dk) for exp2 softmax), z=1 -> k, z=2 -> v
  gemm_bt<short><<<dim3(32, 8, 3), 512, 0, stream>>>(xc, TEN, wt, WEL, bq, bk, bv,
                                                     qkv, TEN, 0.125f * 1.44269504f);
  vtrans<<<dim3(32, 32), 256, 0, stream>>>(qkv + 2 * TEN, vtr);
  flash<<<dim3(16, 32), 512, 0, stream>>>(qkv, qkv + TEN, vtr, comb);
  gemm64_bt<float><<<dim3(64, 8), 512, 0, stream>>>(comb, wt + 3 * WEL, bo, out, 1.0f);
  (void)in_sizes; (void)n_in; (void)out_size; (void)ws_size;
}

// Round 12
// 206.361 us; speedup vs baseline: 1.0447x; 1.0447x over previous
//
#include <hip/hip_runtime.h>
#include <stdint.h>

#define DM   1024
#define NH   16
#define DKH  64
#define SEQ  2048
#define NB   2

typedef __attribute__((ext_vector_type(8))) short  frag8;
typedef __attribute__((ext_vector_type(4))) short  frag4;
typedef __attribute__((ext_vector_type(4))) short  short4v;
typedef __attribute__((ext_vector_type(8))) short  short8v;
typedef __attribute__((ext_vector_type(4))) float  f32x4;

__device__ __forceinline__ unsigned short f2bf(float x){
  unsigned u = __float_as_uint(x);
  u += 0x7fffu + ((u >> 16) & 1u);
  return (unsigned short)(u >> 16);
}

// exp2 via the raw intrinsic (v_exp_f32) — avoids glibc __exp2f macro collision
__device__ __forceinline__ float dev_exp2(float x){
  return __builtin_amdgcn_exp2f(x);
}

#define GLOAD16(GP, LP) __builtin_amdgcn_global_load_lds( \
    (__attribute__((address_space(1))) void*)(GP), \
    (__attribute__((address_space(3))) void*)(LP), 16, 0, 0)

// Compiler memory fence (zero instructions): raw s_barrier is NOT an LLVM memory
// fence, so dependent LDS reads can be hoisted above it. Pin them below.
#define LDSFENCE() do{ asm volatile("" ::: "memory"); \
                       __builtin_amdgcn_sched_barrier(0); }while(0)

// NOTE (bisect r0-r5): v_cvt_pk_bf16_f32 inline-asm pack FAILED 3/3; manual
// element-wise pack passed every time. r10: or/shift u32 pack REGRESSED 5%.
// NOTE (r7): occupancy from waves/block, not more blocks per head.
// NOTE (r8/r9/r10): 8-wave same-grid transform won on flash, gemm_bt, gemm64_bt.
// NOTE (r11): castw mega-fusion REGRESSED +4.5us (12288 early-return blocks +
// LDS overallocation) -> reverted. r12: vtrans fused into gemm_bt z==2 epilogue
// (in-LDS transpose, SMEM reuse), vtrans kernel deleted.

// 16B XOR swizzle: LDS granule g of row r holds global granule g^(r&7);
// staging loads global granule (lane&7)^row. (R4: conflicts -> 0 on b128 reads.)

// ---------------- cast fp32 -> bf16 for Q,K,V ----------------
__global__ __launch_bounds__(256) void cast_qkv(const float* __restrict__ Q,
                                                const float* __restrict__ K,
                                                const float* __restrict__ V,
                                                short* __restrict__ dst){
  const int z = blockIdx.z;
  const float* src = (z == 0) ? Q : (z == 1 ? K : V);
  const int i = (blockIdx.x * 256 + threadIdx.x) * 4;
  float4 f = *(const float4*)(src + i);
  short4v s;
  s.x = (short)f2bf(f.x); s.y = (short)f2bf(f.y);
  s.z = (short)f2bf(f.z); s.w = (short)f2bf(f.w);
  *(short4v*)(dst + (long)z * (SEQ*NB*DM) + i) = s;
}

// ---------------- weight transpose + cast: W(K,N) -> Wt(N,K) bf16 ----------------
__global__ __launch_bounds__(256) void wtrans(const float* __restrict__ Wq,
                                              const float* __restrict__ Wk,
                                              const float* __restrict__ Wv,
                                              const float* __restrict__ Wo,
                                              short* __restrict__ wt){
  const int z = blockIdx.z;
  const float* W = (z == 0) ? Wq : (z == 1 ? Wk : (z == 2 ? Wv : Wo));
  short* out = wt + (long)z * (DM*DM);
  __shared__ float t[32][33];
  const int n0 = blockIdx.x * 32, k0 = blockIdx.y * 32;
  const int c = threadIdx.x & 31, r0 = threadIdx.x >> 5;
#pragma unroll
  for (int i = 0; i < 4; ++i){
    int r = r0 + i * 8;
    t[r][c] = W[(k0 + r) * DM + n0 + c];
  }
  __syncthreads();
#pragma unroll
  for (int i = 0; i < 4; ++i){
    int r = r0 + i * 8;
    out[(n0 + r) * DM + k0 + c] = (short)f2bf(t[c][r]);
  }
}

// ---------------- 128x128 bf16 MFMA GEMM: C = A(M,K) * Bt(N,K)^T, +bias, *scale ----
// 8 waves/block (512 thr), wave = 32x64 sub-tile. 2-buffer counted vmcnt(4).
// z==2 (v-projection): output written DIRECTLY in (B,H,Dk,S) layout via in-LDS
// transpose (SMEM reused; pitch 136 shorts for 16B-aligned rows). Replaces the
// standalone vtrans kernel.
__device__ __forceinline__ void store_out(short* p, float v){ *p = (short)f2bf(v); }
__device__ __forceinline__ void store_out(float* p, float v){ *p = v; }

template<typename OT>
__global__ __launch_bounds__(512) void gemm_bt(const short* __restrict__ Abase, long Astride,
                                               const short* __restrict__ Btbase, long Btstride,
                                               const float* __restrict__ bias0,
                                               const float* __restrict__ bias1,
                                               const float* __restrict__ bias2,
                                               OT* __restrict__ Cbase, long Cstride,
                                               short* __restrict__ vtr,
                                               float qscale){
  const int z = blockIdx.z;
  const short* A  = Abase + (long)z * Astride;
  const short* Bt = Btbase + (long)z * Btstride;
  OT* C = Cbase + (long)z * Cstride;
  const float* bias = (z == 0) ? bias0 : (z == 1 ? bias1 : bias2);
  const float scale = (z == 0) ? qscale : 1.0f;
  const int KD = DM, ND = DM;

  __shared__ __align__(16) short SMEM[4 * 128 * 64];   // As[2] | Bs[2], 64KB
#define AS_(BSEL, IDX) SMEM[(BSEL) * 8192 + (IDX)]
#define BSS(BSEL, IDX) SMEM[16384 + (BSEL) * 8192 + (IDX)]

  const int tid = threadIdx.x;
  const int w = tid >> 6, lane = tid & 63, l15 = lane & 15, quad = lane >> 4;
  const int wy = w >> 1, wx = w & 1;            // 4 x 2 wave grid, 32x64 each
  const int bm = blockIdx.x * 128, bn = blockIdx.y * 128;
  const int lrow = lane >> 3;
  const int lcolsw = (((lane & 7) ^ lrow) & 7) * 8;   // swizzled source granule

  f32x4 acc[2][4] = {};

#define GSTAGE(KT, BSEL) do{                                                    \
  _Pragma("unroll")                                                             \
  for (int i_ = 0; i_ < 2; ++i_){                                               \
    int j_ = w * 2 + i_;                                                        \
    GLOAD16(A  + (bm + j_ * 8 + lrow) * KD + (KT) * 64 + lcolsw,                \
            &AS_(BSEL, j_ * 512));                                              \
    GLOAD16(Bt + (bn + j_ * 8 + lrow) * KD + (KT) * 64 + lcolsw,                \
            &BSS(BSEL, j_ * 512));                                              \
  } }while(0)

#define GCOMPUTE(BS) do{                                                        \
  _Pragma("unroll") for (int ks = 0; ks < 2; ++ks){                             \
    frag8 af[2], bf_[4];                                                        \
    _Pragma("unroll") for (int mt = 0; mt < 2; ++mt)                            \
      af[mt] = *(const frag8*)&AS_(BS, (wy * 32 + mt * 16 + l15) * 64 +         \
                                       (((ks * 4 + quad) ^ (l15 & 7)) * 8));    \
    _Pragma("unroll") for (int nt = 0; nt < 4; ++nt)                            \
      bf_[nt] = *(const frag8*)&BSS(BS, (wx * 64 + nt * 16 + l15) * 64 +        \
                                        (((ks * 4 + quad) ^ (l15 & 7)) * 8));   \
    _Pragma("unroll") for (int mt = 0; mt < 2; ++mt)                            \
      _Pragma("unroll") for (int nt = 0; nt < 4; ++nt)                          \
        acc[mt][nt] = __builtin_amdgcn_mfma_f32_16x16x32_bf16(                  \
            af[mt], bf_[nt], acc[mt][nt], 0, 0, 0);                             \
  } }while(0)

  GSTAGE(0, 0);
  for (int t = 0; t < KD / 64 - 1; ++t){       // 15 pipelined iterations
    GSTAGE(t + 1, (t + 1) & 1);
    asm volatile("s_waitcnt vmcnt(4)" ::: "memory");
    __builtin_amdgcn_s_barrier();
    LDSFENCE();
    GCOMPUTE(t & 1);
    asm volatile("s_waitcnt lgkmcnt(0)" ::: "memory");
    __builtin_amdgcn_sched_barrier(0);
    __builtin_amdgcn_s_barrier();
  }
  asm volatile("s_waitcnt vmcnt(0)" ::: "memory");
  __builtin_amdgcn_s_barrier();
  LDSFENCE();
  GCOMPUTE(1);                                  // tile 15 (odd)

#undef GSTAGE
#undef GCOMPUTE

  if (vtr == nullptr || z != 2){
#pragma unroll
    for (int mt = 0; mt < 2; ++mt){
#pragma unroll
      for (int r = 0; r < 4; ++r){
        int m = bm + wy * 32 + mt * 16 + quad * 4 + r;
#pragma unroll
        for (int nt = 0; nt < 4; ++nt){
          int n = bn + wx * 64 + nt * 16 + l15;
          float v = (acc[mt][nt][r] + bias[n]) * scale;
          store_out(&C[(long)m * ND + n], v);
        }
      }
    }
  } else {
    // ---- v-projection: write (B,H,Dk,S) directly via in-LDS transpose ----
    const int PIT = 136;                       // shorts; 272B rows (16B-aligned)
    short* T = SMEM;                           // 128*136*2 = 34816B <= 64KB
    asm volatile("s_waitcnt lgkmcnt(0)" ::: "memory");
    __builtin_amdgcn_s_barrier();              // all waves done reading SMEM
    LDSFENCE();
#pragma unroll
    for (int mt = 0; mt < 2; ++mt){
#pragma unroll
      for (int nt = 0; nt < 4; ++nt){
        int n = wx * 64 + nt * 16 + l15;
        int m0 = wy * 32 + mt * 16 + quad * 4;
        short4v v4;
#pragma unroll
        for (int r = 0; r < 4; ++r)
          v4[r] = (short)f2bf(acc[mt][nt][r] + bias[bn + n]);
        *(short4v*)&T[n * PIT + m0] = v4;      // T[n][m], 8B write
      }
    }
    asm volatile("s_waitcnt lgkmcnt(0)" ::: "memory");
    __builtin_amdgcn_s_barrier();
    LDSFENCE();
    const int b_ = bm >> 11, s0 = bm & (SEQ - 1);
#pragma unroll
    for (int it = 0; it < 4; ++it){
      int c = it * 512 + tid;
      int nl = c >> 4, ms = (c & 15) * 8;
      short8v v8 = *(const short8v*)&T[nl * PIT + ms];
      int h_ = (bn >> 6) + (nl >> 6), dk = nl & 63;
      *(short8v*)(vtr + ((long)(b_ * 16 + h_) * 64 + dk) * SEQ + s0 + ms) = v8;
    }
  }
#undef AS_
#undef BSS
}

// ---------------- 64x128-tile GEMM (for low-block-count output projection) -------
// 8 waves/block (512 thr), wave = 16x64 (acc[1][4]); counted vmcnt(3). (r10)
template<typename OT>
__global__ __launch_bounds__(512) void gemm64_bt(const short* __restrict__ A,
                                                 const short* __restrict__ Bt,
                                                 const float* __restrict__ bias,
                                                 OT* __restrict__ C,
                                                 float scale){
  const int KD = DM, ND = DM;
  __shared__ __align__(16) short As[2][64 * 64];
  __shared__ __align__(16) short Bs[2][128 * 64];
  const int tid = threadIdx.x;
  const int w = tid >> 6, lane = tid & 63, l15 = lane & 15, quad = lane >> 4;
  const int wy = w >> 1, wx = w & 1;            // 4 x 2 wave grid, 16x64 each
  const int bm = blockIdx.x * 64, bn = blockIdx.y * 128;
  const int lrow = lane >> 3;
  const int lcolsw = (((lane & 7) ^ lrow) & 7) * 8;
  f32x4 acc[4] = {};

#define GSTAGE64(KT, BSEL) do{                                                  \
  {                                                                             \
    int j_ = w;                                                                 \
    GLOAD16(A + (bm + j_ * 8 + lrow) * KD + (KT) * 64 + lcolsw,                 \
            &As[BSEL][j_ * 512]);                                               \
  }                                                                             \
  _Pragma("unroll")                                                             \
  for (int i_ = 0; i_ < 2; ++i_){                                               \
    int j_ = w * 2 + i_;                                                        \
    GLOAD16(Bt + (bn + j_ * 8 + lrow) * KD + (KT) * 64 + lcolsw,                \
            &Bs[BSEL][j_ * 512]);                                               \
  } }while(0)

#define GCOMPUTE64(BS) do{                                                      \
  _Pragma("unroll") for (int ks = 0; ks < 2; ++ks){                             \
    frag8 af, bf_[4];                                                           \
    af = *(const frag8*)&As[BS][(wy * 16 + l15) * 64 +                          \
                                (((ks * 4 + quad) ^ (l15 & 7)) * 8)];           \
    _Pragma("unroll") for (int nt = 0; nt < 4; ++nt)                            \
      bf_[nt] = *(const frag8*)&Bs[BS][(wx * 64 + nt * 16 + l15) * 64 +         \
                                       (((ks * 4 + quad) ^ (l15 & 7)) * 8)];    \
    _Pragma("unroll") for (int nt = 0; nt < 4; ++nt)                            \
      acc[nt] = __builtin_amdgcn_mfma_f32_16x16x32_bf16(                        \
          af, bf_[nt], acc[nt], 0, 0, 0);                                       \
  } }while(0)

  GSTAGE64(0, 0);
  for (int t = 0; t < KD / 64 - 1; ++t){
    GSTAGE64(t + 1, (t + 1) & 1);
    asm volatile("s_waitcnt vmcnt(3)" ::: "memory");
    __builtin_amdgcn_s_barrier();
    LDSFENCE();
    GCOMPUTE64(t & 1);
    asm volatile("s_waitcnt lgkmcnt(0)" ::: "memory");
    __builtin_amdgcn_sched_barrier(0);
    __builtin_amdgcn_s_barrier();
  }
  asm volatile("s_waitcnt vmcnt(0)" ::: "memory");
  __builtin_amdgcn_s_barrier();
  LDSFENCE();
  GCOMPUTE64(1);

#undef GSTAGE64
#undef GCOMPUTE64

#pragma unroll
  for (int r = 0; r < 4; ++r){
    int m = bm + wy * 16 + quad * 4 + r;
#pragma unroll
    for (int nt = 0; nt < 4; ++nt){
      int n = bn + wx * 64 + nt * 16 + l15;
      store_out(&C[(long)m * ND + n], (acc[nt][r] + bias[n]) * scale);
    }
  }
}

// ---------------- flash attention v16 (r9/r11, proven 47.2us) ---------------------
// 8 waves/block (512 thr), QBLK=128, 16 Q-rows/wave; grid 512 blocks; LDS 48KB
// 3-buffer depth-2 counted vmcnt(4); K-permutation + XOR swizzle + ELEMENT-WISE
// manual pack.
__global__ __launch_bounds__(512) void flash(const short* __restrict__ q,
                                             const short* __restrict__ k,
                                             const short* __restrict__ vt,
                                             short* __restrict__ comb){
  const int bh = blockIdx.y;
  const int b = bh >> 4, h = bh & 15;
  const int q0 = blockIdx.x * 128;         // 128 Q-rows per block, 16 per wave
  const int tid = threadIdx.x;
  const int w = tid >> 6, lane = tid & 63, l15 = lane & 15, quad = lane >> 4;

  __shared__ __align__(16) short Ks[3][64 * 64];
  __shared__ __align__(16) short Vs[3][64 * 64];

  // preload Q fragments straight from global (used as MFMA B operand)
  frag8 aq[2];
  const short* qb = q + ((long)(b * SEQ + q0 + w * 16)) * DM + h * DKH;
#pragma unroll
  for (int ks = 0; ks < 2; ++ks)
    aq[ks] = *(const frag8*)(qb + l15 * DM + ks * 32 + quad * 8);

  frag8 ones8;
#pragma unroll
  for (int e = 0; e < 8; ++e) ones8[e] = (short)0x3F80;  // bf16 1.0

  f32x4 O[4] = {};
  f32x4 Lacc = {0.f, 0.f, 0.f, 0.f};

  const short* kb  = k + ((long)b * SEQ) * DM + h * DKH;
  const short* vtb = vt + (long)bh * (DKH * SEQ);
  const int lrow8 = lane >> 3;
  const int lcolsw = (((lane & 7) ^ lrow8) & 7) * 8;   // 16B XOR swizzle

// stage tile KT into buffer BSEL; each of the 8 waves stages 8 K-rows + 8 V-rows.
// K rows permuted per the frag8-PV layout: LDS row p holds key
// a(p) = 32*(p>>5) + 8*((p>>2)&3) + 4*((p>>4)&1) + (p&3), p = jj*8+lrow8, jj=w.
#define STAGE(KT, BSEL) do{                                                     \
  int jj_ = w;                                                                  \
  int kr_ = 32 * (jj_ >> 2) + 8 * ((jj_ * 2 + (lrow8 >> 2)) & 3)                \
          + 4 * ((jj_ >> 1) & 1) + (lrow8 & 3);                                 \
  GLOAD16(kb  + ((KT) * 64 + kr_) * DM + lcolsw,        &Ks[BSEL][jj_ * 512]);  \
  GLOAD16(vtb + (jj_ * 8 + lrow8) * SEQ + (KT) * 64 + lcolsw,                   \
          &Vs[BSEL][jj_ * 512]);                                                \
}while(0)

#define COMPUTE(BS) do{                                                         \
  __builtin_amdgcn_s_setprio(1);                                                \
  f32x4 scT[4];                                                                 \
  _Pragma("unroll") for (int nt = 0; nt < 4; ++nt)                              \
    scT[nt] = (f32x4){0.f, 0.f, 0.f, 0.f};                                      \
  _Pragma("unroll") for (int ks = 0; ks < 2; ++ks){                             \
    _Pragma("unroll") for (int nt = 0; nt < 4; ++nt){                           \
      frag8 ak = *(const frag8*)&Ks[BS][(nt * 16 + l15) * 64 +                  \
                                        (((ks * 4 + quad) ^ (l15 & 7)) * 8)];   \
      scT[nt] = __builtin_amdgcn_mfma_f32_16x16x32_bf16(                        \
          ak, aq[ks], scT[nt], 0, 0, 0);                                        \
    }                                                                           \
  }                                                                             \
  frag8 ap8[2];                                                                 \
  _Pragma("unroll") for (int c2 = 0; c2 < 2; ++c2){                             \
    frag8 p8;                                                                   \
    _Pragma("unroll") for (int hf = 0; hf < 2; ++hf)                            \
      _Pragma("unroll") for (int r = 0; r < 4; ++r){                            \
        float e = dev_exp2(scT[2 * c2 + hf][r]);                                \
        p8[hf * 4 + r] = (short)((__float_as_uint(e) + 0x8000u) >> 16);         \
      }                                                                         \
    ap8[c2] = p8;                                                               \
  }                                                                             \
  _Pragma("unroll") for (int c2 = 0; c2 < 2; ++c2){                             \
    _Pragma("unroll") for (int dt = 0; dt < 4; ++dt){                           \
      frag8 bv8 = *(const frag8*)&Vs[BS][(dt * 16 + l15) * 64 +                 \
                                         (((c2 * 4 + quad) ^ (l15 & 7)) * 8)];  \
      O[dt] = __builtin_amdgcn_mfma_f32_16x16x32_bf16(                          \
          ap8[c2], bv8, O[dt], 0, 0, 0);                                        \
    }                                                                           \
    Lacc = __builtin_amdgcn_mfma_f32_16x16x32_bf16(                             \
        ap8[c2], ones8, Lacc, 0, 0, 0);                                         \
  }                                                                             \
  __builtin_amdgcn_s_setprio(0);                                                \
}while(0)

// stage KT+2, wait tile KT (vmcnt(4): leaves the 4 loads of KT+1/KT+2 in
// flight), barrier, fence, compute KT, lgkm-drain + barrier (WAR publish)
#define ITER(KT, BC, BSNEXT) do{                                                \
  STAGE((KT) + 2, BSNEXT);                                                      \
  asm volatile("s_waitcnt vmcnt(4)" ::: "memory");                              \
  __builtin_amdgcn_s_barrier();                                                 \
  LDSFENCE();                                                                   \
  COMPUTE(BC);                                                                  \
  asm volatile("s_waitcnt lgkmcnt(0)" ::: "memory");                            \
  __builtin_amdgcn_sched_barrier(0);                                            \
  __builtin_amdgcn_s_barrier();                                                 \
}while(0)

  STAGE(0, 0);
  STAGE(1, 1);
  for (int kt = 0; kt < SEQ / 64 - 2; kt += 3){   // 30 iterations, tiles 0..29
    ITER(kt,     0, 2);
    ITER(kt + 1, 1, 0);
    ITER(kt + 2, 2, 1);
  }
  // epilogue: tiles 30 (buf 0) and 31 (buf 1), no further staging
  asm volatile("s_waitcnt vmcnt(2)" ::: "memory");
  __builtin_amdgcn_s_barrier();
  LDSFENCE();
  COMPUTE(0);
  asm volatile("s_waitcnt vmcnt(0)" ::: "memory");
  __builtin_amdgcn_s_barrier();
  LDSFENCE();
  COMPUTE(1);

#undef ITER
#undef COMPUTE
#undef STAGE

  // epilogue: O/l -> comb bf16  (C-layout: row = quad*4+r = qrow, col = l15 = d)
  short* ob = comb + ((long)(b * SEQ + q0 + w * 16)) * DM + h * DKH;
#pragma unroll
  for (int r = 0; r < 4; ++r){
    float inv = 1.f / Lacc[r];
#pragma unroll
    for (int dt = 0; dt < 4; ++dt)
      ob[(quad * 4 + r) * DM + dt * 16 + l15] = (short)f2bf(O[dt][r] * inv);
  }
}

// ---------------- launch ----------------
extern "C" void kernel_launch(void* const* d_in, const int* in_sizes, int n_in,
                              void* d_out, int out_size, void* d_ws, size_t ws_size,
                              hipStream_t stream){
  const float* Q  = (const float*)d_in[0];
  const float* K  = (const float*)d_in[1];
  const float* V  = (const float*)d_in[2];
  const float* Wq = (const float*)d_in[3];
  const float* bq = (const float*)d_in[4];
  const float* Wk = (const float*)d_in[5];
  const float* bk = (const float*)d_in[6];
  const float* Wv = (const float*)d_in[7];
  const float* bv = (const float*)d_in[8];
  const float* Wo = (const float*)d_in[9];
  const float* bo = (const float*)d_in[10];
  float* out = (float*)d_out;

  const long TEN = (long)NB * SEQ * DM;   // 4194304 elements per activation tensor
  const long WEL = (long)DM * DM;         // 1048576 per weight
  short* ws   = (short*)d_ws;
  short* xc   = ws;                 // 3 * TEN
  short* wt   = xc + 3 * TEN;       // 4 * WEL
  short* qkv  = wt + 4 * WEL;       // 3 * TEN   (q, k projections; v slot unused)
  short* vtr  = qkv + 3 * TEN;      // TEN       (B,H,Dk,S) — written by gemm_bt z=2
  short* comb = vtr + TEN;          // TEN

  cast_qkv<<<dim3(4096, 1, 3), 256, 0, stream>>>(Q, K, V, xc);
  wtrans<<<dim3(32, 32, 4), 256, 0, stream>>>(Wq, Wk, Wv, Wo, wt);
  // projections: z=0 -> q (scaled by log2e/sqrt(Dk)), z=1 -> k, z=2 -> v (writes vtr directly)
  gemm_bt<short><<<dim3(32, 8, 3), 512, 0, stream>>>(xc, TEN, wt, WEL, bq, bk, bv,
                                                     qkv, TEN, vtr, 0.125f * 1.44269504f);
  flash<<<dim3(16, 32), 512, 0, stream>>>(qkv, qkv + TEN, vtr, comb);
  gemm64_bt<float><<<dim3(64, 8), 512, 0, stream>>>(comb, wt + 3 * WEL, bo, out, 1.0f);
  (void)in_sizes; (void)n_in; (void)out_size; (void)ws_size;
}